// Round 4
// baseline (82.141 us; speedup 1.0000x reference)
//
#include <hip/hip_runtime.h>
#include <math.h>

#define BATCH 8
#define NPTS  4096
#define TPB   256
#define ROWS  256                 // query rows per block
#define NRC   (NPTS / ROWS)       // 16 row chunks
#define CPT   (NPTS / TPB)        // 16 candidates packed per thread

typedef __bf16 bf16x8 __attribute__((ext_vector_type(8)));
typedef float  f32x16 __attribute__((ext_vector_type(16)));

// Fully-fused chamfer: one kernel, one dispatch. Each block = (row chunk,
// batch, dir) and scans ALL 4096 candidates from LDS (128 KB sB -> 1
// block/CU; grid is exactly 256 blocks = 1/CU so nothing is displaced).
// Split-precision MFMA packing (verified absmax 0 in rounds 2-3):
//   A[q]: k0-2=hi(q), k3-5=hi(q), k8-10=lo(q), k11=k12=1
//   B[c]: k0-2=hi(-2c), k3-5=lo(-2c), k8-10=hi(-2c), k11=hi(y2), k12=lo(y2)
// => D = ||c||^2 - 2 q.c (lo*lo dropped). Per-pair cost: one v_min3 slot.
// Row-min via XOR-swizzled LDS transpose; + ||q||^2, clamp, block-sum,
// single atomicAdd per block. No workspace, no phase-2 kernel.
__global__ __launch_bounds__(TPB, 1) void chamfer_fused_kernel(
    const float* __restrict__ input,
    const float* __restrict__ target,
    float* __restrict__ out)
{
  const int dir = blockIdx.z, b = blockIdx.y, rc = blockIdx.x;

  const float* __restrict__ qp = (dir ? target : input) + (size_t)b * NPTS * 3;
  const float* __restrict__ cp = (dir ? input  : target) + (size_t)b * NPTS * 3;

  // k-half-major: each lane's fragment is ONE conflict-free ds_read_b128.
  __shared__ bf16x8 sB[2][NPTS];    // 128 KB (reused as f32 scratch after loop)
  __shared__ bf16x8 sA[2][ROWS];    //   8 KB
  __shared__ float  wsum[TPB / 64];

  // --- pack candidates: 16 consecutive cols per thread (48 floats = 12 float4)
  {
    const int c0 = (int)threadIdx.x * CPT;
    const float4* __restrict__ cv = (const float4*)(cp + 3 * c0);
    float f[3 * CPT];
    #pragma unroll
    for (int i = 0; i < (3 * CPT) / 4; ++i) {
      const float4 t = cv[i];
      f[4 * i + 0] = t.x; f[4 * i + 1] = t.y;
      f[4 * i + 2] = t.z; f[4 * i + 3] = t.w;
    }
    #pragma unroll
    for (int j = 0; j < CPT; ++j) {
      const float x = f[3 * j], y = f[3 * j + 1], z = f[3 * j + 2];
      const float mx = -2.f * x, my = -2.f * y, mz = -2.f * z;
      const __bf16 hx = (__bf16)mx, hy = (__bf16)my, hz = (__bf16)mz;
      const __bf16 lx = (__bf16)(mx - (float)hx);
      const __bf16 ly = (__bf16)(my - (float)hy);
      const __bf16 lz = (__bf16)(mz - (float)hz);
      const float y2 = fmaf(x, x, fmaf(y, y, z * z));
      const __bf16 h2 = (__bf16)y2, l2 = (__bf16)(y2 - (float)h2);
      const __bf16 z0 = (__bf16)0.f;
      bf16x8 v0, v1;
      v0[0]=hx; v0[1]=hy; v0[2]=hz; v0[3]=lx; v0[4]=ly; v0[5]=lz; v0[6]=z0; v0[7]=z0;
      v1[0]=hx; v1[1]=hy; v1[2]=hz; v1[3]=h2; v1[4]=l2; v1[5]=z0; v1[6]=z0; v1[7]=z0;
      sB[0][c0 + j] = v0;
      sB[1][c0 + j] = v1;
    }
  }
  // --- pack queries: 1 row per thread; keep q in regs for the x2 epilogue
  float qx, qy, qz;
  {
    const int r = rc * ROWS + (int)threadIdx.x;
    qx = qp[3*r]; qy = qp[3*r+1]; qz = qp[3*r+2];
    const __bf16 hx = (__bf16)qx, hy = (__bf16)qy, hz = (__bf16)qz;
    const __bf16 lx = (__bf16)(qx - (float)hx);
    const __bf16 ly = (__bf16)(qy - (float)hy);
    const __bf16 lz = (__bf16)(qz - (float)hz);
    const __bf16 z0 = (__bf16)0.f, o1 = (__bf16)1.f;
    bf16x8 v0, v1;
    v0[0]=hx; v0[1]=hy; v0[2]=hz; v0[3]=hx; v0[4]=hy; v0[5]=hz; v0[6]=z0; v0[7]=z0;
    v1[0]=lx; v1[1]=ly; v1[2]=lz; v1[3]=o1; v1[4]=o1; v1[5]=z0; v1[6]=z0; v1[7]=z0;
    sA[0][threadIdx.x] = v0;
    sA[1][threadIdx.x] = v1;
  }
  __syncthreads();

  const int lane = (int)threadIdx.x & 63;
  const int wave = (int)threadIdx.x >> 6;
  const int half = lane >> 5;          // which K-half this lane supplies
  const int l31  = lane & 31;

  // Each wave owns 64 rows = 2 row-strips; each B-frag read feeds 2 MFMAs.
  const bf16x8 a0 = sA[half][wave * 64 + l31];
  const bf16x8 a1 = sA[half][wave * 64 + 32 + l31];

  float rm0[16], rm1[16];
  #pragma unroll
  for (int i = 0; i < 16; ++i) { rm0[i] = 3.4e38f; rm1[i] = 3.4e38f; }

  f32x16 zacc;
  #pragma unroll
  for (int i = 0; i < 16; ++i) zacc[i] = 0.f;

  #pragma unroll 4
  for (int m = 0; m < NPTS / 32; m += 2) {         // 128 col-tiles, 2/iter
    const bf16x8 bfA = sB[half][m * 32 + l31];
    const bf16x8 bfB = sB[half][m * 32 + 32 + l31];
    const f32x16 dA0 = __builtin_amdgcn_mfma_f32_32x32x16_bf16(a0, bfA, zacc, 0, 0, 0);
    const f32x16 dA1 = __builtin_amdgcn_mfma_f32_32x32x16_bf16(a1, bfA, zacc, 0, 0, 0);
    const f32x16 dB0 = __builtin_amdgcn_mfma_f32_32x32x16_bf16(a0, bfB, zacc, 0, 0, 0);
    const f32x16 dB1 = __builtin_amdgcn_mfma_f32_32x32x16_bf16(a1, bfB, zacc, 0, 0, 0);
    #pragma unroll
    for (int i = 0; i < 16; ++i) {
      rm0[i] = fminf(fminf(dA0[i], dB0[i]), rm0[i]);   // -> v_min3_f32
      rm1[i] = fminf(fminf(dA1[i], dB1[i]), rm1[i]);
    }
  }

  // --- row-min finalize via LDS transpose (reuse sB as [256][32] f32,
  // XOR-swizzled col ^= (row&7)<<2 -> 2-way conflicts only = free).
  __syncthreads();                     // everyone done reading sB/sA
  float* __restrict__ scr = (float*)sB;
  #pragma unroll
  for (int r = 0; r < 16; ++r) {
    // D layout: row = (r&3) + 8*(r>>2) + 4*half, col = l31.
    const int row0 = wave * 64 + (r & 3) + 8 * (r >> 2) + 4 * half;
    const int sw   = ((row0 & 7) << 2);        // row0&7 == row1&7
    scr[row0 * 32 + (l31 ^ sw)]        = rm0[r];
    scr[(row0 + 32) * 32 + (l31 ^ sw)] = rm1[r];
  }
  __syncthreads();

  // Thread t owns output row t: 8 swizzled b128 reads + min tree, then
  // + ||q||^2 (monotone-safe) and the ref's clamp.
  const int t = (int)threadIdx.x;
  const float4* __restrict__ rp = (const float4*)(scr + t * 32);
  float mn = 3.4e38f;
  #pragma unroll
  for (int k = 0; k < 8; ++k) {
    const float4 v = rp[k ^ (t & 7)];
    mn = fminf(mn, fminf(fminf(v.x, v.y), fminf(v.z, v.w)));
  }
  const float x2 = fmaf(qx, qx, fmaf(qy, qy, qz * qz));
  float s = fmaxf(mn + x2, 0.f);

  // --- block sum -> one atomicAdd per block (256 total)
  #pragma unroll
  for (int off = 32; off > 0; off >>= 1)
    s += __shfl_down(s, off, 64);
  if ((threadIdx.x & 63) == 0) wsum[threadIdx.x >> 6] = s;
  __syncthreads();
  if (threadIdx.x == 0) {
    const float v = wsum[0] + wsum[1] + wsum[2] + wsum[3];
    atomicAdd(out, v * (1.0f / (float)(BATCH * NPTS)));
  }
}

extern "C" void kernel_launch(void* const* d_in, const int* in_sizes, int n_in,
                              void* d_out, int out_size, void* d_ws, size_t ws_size,
                              hipStream_t stream) {
  const float* input  = (const float*)d_in[0];   // [B, N, 3] fp32
  const float* target = (const float*)d_in[1];   // [B, M, 3] fp32
  float* out = (float*)d_out;
  (void)d_ws; (void)ws_size;                     // workspace unused

  hipMemsetAsync(out, 0, sizeof(float), stream);

  dim3 grid(NRC, BATCH, 2);                      // 16 x 8 x 2 = 256 blocks
  chamfer_fused_kernel<<<grid, dim3(TPB), 0, stream>>>(input, target, out);
}

// Round 5
// 72.890 us; speedup vs baseline: 1.1269x; 1.1269x over previous
//
#include <hip/hip_runtime.h>
#include <math.h>

#define BATCH 8
#define NPTS  4096
#define TPB   256
#define NCC   4                   // candidate chunks
#define CHUNK (NPTS / NCC)        // 1024 candidates per block
#define ROWS  256                 // query rows per block
#define NRC   (NPTS / ROWS)       // 16 row chunks

typedef __bf16 bf16x8 __attribute__((ext_vector_type(8)));
typedef float  f32x16 __attribute__((ext_vector_type(16)));

// Measured-best structure (R3, 74.7 us): two kernels, 40 KB LDS -> exactly
// 4 blocks/CU (160 KB) = 4 waves/SIMD so MFMA/ds_read latency is hidden
// (the R4 fused 1-wave/SIMD variant exposed it and regressed 7.4 us).
// One mfma_f32_32x32x16_bf16 per 32x32 tile computes S = ||c||^2 - 2 q.c in
// split precision packed along K (verified absmax 0):
//   A[q]: k0-2=hi(q), k3-5=hi(q), k8-10=lo(q), k11=k12=1
//   B[c]: k0-2=hi(-2c), k3-5=lo(-2c), k8-10=hi(-2c), k11=hi(y2), k12=lo(y2)
// Per-pair epilogue is one v_min3 slot. Row-min via XOR-swizzled LDS
// transpose (2-way conflicts = free). ||q||^2 + clamp fused here (monotone,
// commutes bit-exactly with the min over cc chunks done in phase 2).
__global__ __launch_bounds__(TPB) void chamfer_mfma_kernel(
    const float* __restrict__ input,
    const float* __restrict__ target,
    float* __restrict__ part)     // [2][BATCH][NCC][NPTS] f32 = 2 MB
{
  const int dir = blockIdx.z, b = blockIdx.y;
  const int rc = blockIdx.x & (NRC - 1);
  const int cc = blockIdx.x >> 4;                 // NRC == 16

  const float* __restrict__ qp = (dir ? target : input) + (size_t)b * NPTS * 3;
  const float* __restrict__ cp = (dir ? input  : target) + (size_t)b * NPTS * 3;

  // k-half-major: each lane's fragment is ONE conflict-free ds_read_b128.
  __shared__ bf16x8 sB[2][CHUNK];   // 32 KB (reused as f32 scratch after loop)
  __shared__ bf16x8 sA[2][ROWS];    //  8 KB

  // --- pack candidates: 4 consecutive cols per thread (12 floats = 3 float4)
  {
    const int c0 = cc * CHUNK + (int)threadIdx.x * 4;
    const float4* __restrict__ cv = (const float4*)(cp + 3 * c0);
    const float4 f0 = cv[0], f1 = cv[1], f2 = cv[2];
    float xs[4] = { f0.x, f0.w, f1.z, f2.y };
    float ys[4] = { f0.y, f1.x, f1.w, f2.z };
    float zs[4] = { f0.z, f1.y, f2.x, f2.w };
    #pragma unroll
    for (int j = 0; j < 4; ++j) {
      const float mx = -2.f * xs[j], my = -2.f * ys[j], mz = -2.f * zs[j];
      const __bf16 hx = (__bf16)mx, hy = (__bf16)my, hz = (__bf16)mz;
      const __bf16 lx = (__bf16)(mx - (float)hx);
      const __bf16 ly = (__bf16)(my - (float)hy);
      const __bf16 lz = (__bf16)(mz - (float)hz);
      const float y2 = fmaf(xs[j], xs[j], fmaf(ys[j], ys[j], zs[j] * zs[j]));
      const __bf16 h2 = (__bf16)y2, l2 = (__bf16)(y2 - (float)h2);
      const __bf16 z0 = (__bf16)0.f;
      bf16x8 v0, v1;
      v0[0]=hx; v0[1]=hy; v0[2]=hz; v0[3]=lx; v0[4]=ly; v0[5]=lz; v0[6]=z0; v0[7]=z0;
      v1[0]=hx; v1[1]=hy; v1[2]=hz; v1[3]=h2; v1[4]=l2; v1[5]=z0; v1[6]=z0; v1[7]=z0;
      sB[0][threadIdx.x * 4 + j] = v0;
      sB[1][threadIdx.x * 4 + j] = v1;
    }
  }
  // --- pack queries: 1 row per thread; keep q in regs for the x2 epilogue
  float qx, qy, qz;
  {
    const int r = rc * ROWS + (int)threadIdx.x;
    qx = qp[3*r]; qy = qp[3*r+1]; qz = qp[3*r+2];
    const __bf16 hx = (__bf16)qx, hy = (__bf16)qy, hz = (__bf16)qz;
    const __bf16 lx = (__bf16)(qx - (float)hx);
    const __bf16 ly = (__bf16)(qy - (float)hy);
    const __bf16 lz = (__bf16)(qz - (float)hz);
    const __bf16 z0 = (__bf16)0.f, o1 = (__bf16)1.f;
    bf16x8 v0, v1;
    v0[0]=hx; v0[1]=hy; v0[2]=hz; v0[3]=hx; v0[4]=hy; v0[5]=hz; v0[6]=z0; v0[7]=z0;
    v1[0]=lx; v1[1]=ly; v1[2]=lz; v1[3]=o1; v1[4]=o1; v1[5]=z0; v1[6]=z0; v1[7]=z0;
    sA[0][threadIdx.x] = v0;
    sA[1][threadIdx.x] = v1;
  }
  __syncthreads();

  const int lane = (int)threadIdx.x & 63;
  const int wave = (int)threadIdx.x >> 6;
  const int half = lane >> 5;          // which K-half this lane supplies
  const int l31  = lane & 31;

  // Each wave owns 64 rows = 2 row-strips; B-frag reads amortized over 4 MFMAs.
  const bf16x8 a0 = sA[half][wave * 64 + l31];
  const bf16x8 a1 = sA[half][wave * 64 + 32 + l31];

  float rm0[16], rm1[16];
  #pragma unroll
  for (int i = 0; i < 16; ++i) { rm0[i] = 3.4e38f; rm1[i] = 3.4e38f; }

  f32x16 zacc;
  #pragma unroll
  for (int i = 0; i < 16; ++i) zacc[i] = 0.f;

  #pragma unroll
  for (int m = 0; m < CHUNK / 32; m += 2) {        // 16 x (2 col-tiles)
    const bf16x8 bfA = sB[half][m * 32 + l31];
    const bf16x8 bfB = sB[half][m * 32 + 32 + l31];
    const f32x16 dA0 = __builtin_amdgcn_mfma_f32_32x32x16_bf16(a0, bfA, zacc, 0, 0, 0);
    const f32x16 dA1 = __builtin_amdgcn_mfma_f32_32x32x16_bf16(a1, bfA, zacc, 0, 0, 0);
    const f32x16 dB0 = __builtin_amdgcn_mfma_f32_32x32x16_bf16(a0, bfB, zacc, 0, 0, 0);
    const f32x16 dB1 = __builtin_amdgcn_mfma_f32_32x32x16_bf16(a1, bfB, zacc, 0, 0, 0);
    #pragma unroll
    for (int i = 0; i < 16; ++i) {
      rm0[i] = fminf(fminf(dA0[i], dB0[i]), rm0[i]);   // -> v_min3_f32
      rm1[i] = fminf(fminf(dA1[i], dB1[i]), rm1[i]);
    }
  }

  // --- row-min finalize via LDS transpose (reuse sB as [256][32] f32,
  // XOR-swizzled col ^= (row&7)<<2 -> writes & reads are 2-way only = free).
  __syncthreads();                     // everyone done reading sB/sA
  float* __restrict__ scr = (float*)sB;
  #pragma unroll
  for (int r = 0; r < 16; ++r) {
    // D layout: row = (r&3) + 8*(r>>2) + 4*half, col = l31.
    const int row0 = wave * 64 + (r & 3) + 8 * (r >> 2) + 4 * half;
    const int sw   = ((row0 & 7) << 2);        // row0&7 == row1&7
    scr[row0 * 32 + (l31 ^ sw)]        = rm0[r];
    scr[(row0 + 32) * 32 + (l31 ^ sw)] = rm1[r];
  }
  __syncthreads();

  // Thread t owns output row t: 8 swizzled b128 reads + min tree.
  const int t = (int)threadIdx.x;
  const float4* __restrict__ rp = (const float4*)(scr + t * 32);
  float mn = 3.4e38f;
  #pragma unroll
  for (int k = 0; k < 8; ++k) {
    const float4 v = rp[k ^ (t & 7)];
    mn = fminf(mn, fminf(fminf(v.x, v.y), fminf(v.z, v.w)));
  }
  const float x2 = fmaf(qx, qx, fmaf(qy, qy, qz * qz));
  part[((size_t)(dir * BATCH + b) * NCC + cc) * NPTS + rc * ROWS + t] =
      fmaxf(mn + x2, 0.f);
}

// Phase 2: pure min over NCC=4 chunk partials (already x2-added + clamped),
// then mean-reduce. Reads 2 MB (L2-resident), coalesced.
__global__ __launch_bounds__(TPB) void chamfer_reduce_kernel(
    const float* __restrict__ part, float* __restrict__ out)
{
  const int i = (blockIdx.x * TPB + (int)threadIdx.x) * 4;  // [2][B][NPTS] flat
  const int g = i >> 12;
  const int q = i & (NPTS - 1);

  const float* __restrict__ p = part + ((size_t)g * NCC) * NPTS + q;
  float4 mn = *(const float4*)p;
  #pragma unroll
  for (int cc = 1; cc < NCC; ++cc) {
    const float4 v = *(const float4*)(p + (size_t)cc * NPTS);
    mn.x = fminf(mn.x, v.x); mn.y = fminf(mn.y, v.y);
    mn.z = fminf(mn.z, v.z); mn.w = fminf(mn.w, v.w);
  }
  float s = mn.x + mn.y + mn.z + mn.w;
  #pragma unroll
  for (int off = 32; off > 0; off >>= 1)
    s += __shfl_down(s, off, 64);

  __shared__ float wsum[TPB / 64];
  if ((threadIdx.x & 63) == 0) wsum[threadIdx.x >> 6] = s;
  __syncthreads();
  if (threadIdx.x == 0) {
    const float v = wsum[0] + wsum[1] + wsum[2] + wsum[3];
    atomicAdd(out, v * (1.0f / (float)(BATCH * NPTS)));
  }
}

extern "C" void kernel_launch(void* const* d_in, const int* in_sizes, int n_in,
                              void* d_out, int out_size, void* d_ws, size_t ws_size,
                              hipStream_t stream) {
  const float* input  = (const float*)d_in[0];   // [B, N, 3] fp32
  const float* target = (const float*)d_in[1];   // [B, M, 3] fp32
  float* out  = (float*)d_out;
  float* part = (float*)d_ws;                    // [2][BATCH][NCC][NPTS] = 2 MB

  hipMemsetAsync(out, 0, sizeof(float), stream);

  dim3 grid1(NRC * NCC, BATCH, 2);               // 64 x 8 x 2 = 1024 blocks
  chamfer_mfma_kernel<<<grid1, dim3(TPB), 0, stream>>>(input, target, part);

  dim3 grid2((2 * BATCH * NPTS) / (TPB * 4));    // 64 blocks
  chamfer_reduce_kernel<<<grid2, dim3(TPB), 0, stream>>>(part, out);
}